// Round 2
// baseline (2006.679 us; speedup 1.0000x reference)
//
#include <hip/hip_runtime.h>

// H2GCNConv: out[:, 0:128]   = segment_sum(w1 * x[col1], row1)
//            out[:, 128:256] = segment_sum(w2 * x[col2], row2)
// N = 50000, d = 128, out stride = 256 floats.
//
// Round 8: round-7's bucket_accum hit 1860us at VALUBusy 2.2% -- 475 cyc per
// record. Diagnosis: hipcc compiles atomicAdd on __shared__ float to a CAS
// loop (ds_read + ds_cmpst_rtn dependent chain, ~240cy/atomic) because the
// harness doesn't pass -munsafe-fp-atomics. Fix: emit hardware ds_add_f32
// (fire-and-forget, no return) via inline asm. LDS address = low 32 bits of
// the generic shared pointer; plane 1 reached with a free offset:16384
// immediate. Explicit s_waitcnt lgkmcnt(0) before the epilogue barrier since
// the compiler can't track asm DS ops.
// Pipeline: init_fill -> cvt_bf16 -> bin_scatter -> bucket_accum.

#define N_NODES 50000
#define D 128
#define OUT_STRIDE 256

#define BSHIFT 6                       // 64 rows / bucket
#define BROWS (1 << BSHIFT)
#define NBUCK ((N_NODES + BROWS - 1) >> BSHIFT)   // 782
#define CAP1 1408                      // slab cap, graph1 (mean 1023)
#define CAP2 2560                      // slab cap, graph2 (mean 2046)
#define G1TOT (NBUCK * CAP1)
#define CHUNK 7168                     // edges per bin_scatter WG

typedef float vf2 __attribute__((ext_vector_type(2)));

static inline size_t align256(size_t x) { return (x + 255) & ~(size_t)255; }

__device__ __forceinline__ unsigned f32_to_bf16_bits(float f) {
    unsigned u = __float_as_uint(f);
    return (u + 0x7fffu + ((u >> 16) & 1u)) >> 16;   // RNE
}

// ---------------- 1. init slab write cursors (no hist, no scan) ------------

__global__ void init_fill(int* __restrict__ fill) {
    int i = blockIdx.x * blockDim.x + threadIdx.x;
    if (i < NBUCK) {
        fill[i]         = i * CAP1;            // absolute record index
        fill[NBUCK + i] = G1TOT + i * CAP2;
    }
}

// ---------------- 2. binned scatter: edges -> bucket slabs -----------------

__global__ void __launch_bounds__(256) bin_scatter(
        const int* __restrict__ ei1, const float* __restrict__ w1, int E1, int nch1,
        const int* __restrict__ ei2, const float* __restrict__ w2, int E2,
        int* __restrict__ fill, uint2* __restrict__ inter) {
    int g, chunk;
    if ((int)blockIdx.x < nch1) { g = 0; chunk = blockIdx.x; }
    else                        { g = 1; chunk = blockIdx.x - nch1; }
    const int*   ei = g ? ei2 : ei1;
    const float* w  = g ? w2  : w1;
    int E           = g ? E2  : E1;
    int* fcur       = fill + g * NBUCK;
    int e0  = chunk * CHUNK;
    int cnt = min(CHUNK, E - e0);

    __shared__ uint2 stage[CHUNK];              // 56 KB
    __shared__ int cntb[NBUCK], cur[NBUCK], gbase[NBUCK];   // 3 x 3.1 KB
    __shared__ int wsum[4];
    int t = threadIdx.x, lane = t & 63, wid = t >> 6;
    for (int b = t; b < NBUCK; b += 256) cntb[b] = 0;
    __syncthreads();
    // pass 1: count bins
    for (int i = t; i < cnt; i += 256)
        atomicAdd(&cntb[ei[e0 + i] >> BSHIFT], 1);
    __syncthreads();
    // exclusive scan over 782 bins (4 elems/thread, element-ordered quads)
    {
        int i0 = 4 * t;
        int v0 = (i0 + 0 < NBUCK) ? cntb[i0 + 0] : 0;
        int v1 = (i0 + 1 < NBUCK) ? cntb[i0 + 1] : 0;
        int v2 = (i0 + 2 < NBUCK) ? cntb[i0 + 2] : 0;
        int v3 = (i0 + 3 < NBUCK) ? cntb[i0 + 3] : 0;
        int p = v0 + v1 + v2 + v3, s = p;
        #pragma unroll
        for (int d = 1; d < 64; d <<= 1) { int u = __shfl_up(s, d, 64); if (lane >= d) s += u; }
        if (lane == 63) wsum[wid] = s;
        __syncthreads();
        int add = 0;
        #pragma unroll
        for (int k = 0; k < 4; ++k) if (k < wid) add += wsum[k];
        s += add;
        int e = s - p;
        if (i0 + 0 < NBUCK) cur[i0 + 0] = e;
        if (i0 + 1 < NBUCK) cur[i0 + 1] = e + v0;
        if (i0 + 2 < NBUCK) cur[i0 + 2] = e + v0 + v1;
        if (i0 + 3 < NBUCK) cur[i0 + 3] = e + v0 + v1 + v2;
    }
    __syncthreads();
    // reserve slab space per bin (absolute record indices)
    for (int b = t; b < NBUCK; b += 256) {
        int c = cntb[b];
        gbase[b] = c ? atomicAdd(&fcur[b], c) : 0;
    }
    __syncthreads();
    // pass 2: rank + stage
    for (int i = t; i < cnt; i += 256) {
        int row = ei[e0 + i];
        int col = ei[E + e0 + i];
        unsigned rec = (unsigned)col | (f32_to_bf16_bits(w[e0 + i]) << 16);
        int b = row >> BSHIFT;
        int pos = atomicAdd(&cur[b], 1);
        stage[pos] = make_uint2((unsigned)(row & (BROWS - 1)), rec);
    }
    __syncthreads();
    // flush each bin as a contiguous burst (wave per bin, round-robin)
    for (int b = wid; b < NBUCK; b += 4) {
        int c = cntb[b];
        if (!c) continue;
        int s0 = cur[b] - c;          // cur[b] is now end-of-bin in stage
        int gb = gbase[b];
        for (int i = lane; i < c; i += 64)
            inter[gb + i] = stage[s0 + i];
    }
}

// ---------------- 3. x -> bf16x2 pack --------------------------------------

__global__ void cvt_bf16(const float* __restrict__ x, uint2* __restrict__ xb4, int n4) {
    int i = blockIdx.x * blockDim.x + threadIdx.x;
    if (i >= n4) return;
    float4 v = ((const float4*)x)[i];
    unsigned a = f32_to_bf16_bits(v.x);
    unsigned b = f32_to_bf16_bits(v.y);
    unsigned c = f32_to_bf16_bits(v.z);
    unsigned d = f32_to_bf16_bits(v.w);
    xb4[i] = make_uint2(a | (b << 16), c | (d << 16));
}

// ---------------- 4. bucket accumulate: gather + ds_add_f32 + write --------
// One WG per (bucket, graph). 32 KB f32 accumulator, two planes:
//   plane0[row][lane] = col 2*lane, plane1[row][lane] = col 2*lane+1
// so each ds_add_f32 hits 64 consecutive floats (2-way bank alias = free).
// Hardware ds_add_f32 via inline asm: hipcc's atomicAdd on shared float is a
// CAS loop without -munsafe-fp-atomics (round-7 post-mortem: 475 cyc/record).

__device__ __forceinline__ void acc_rec(unsigned accb, int lane,
                                        unsigned rl, unsigned cw, unsigned p) {
    float w  = __int_as_float((int)(cw & 0xffff0000u));   // bf16 bits high
    float lo = __int_as_float((int)(p << 16));
    float hi = __int_as_float((int)(p & 0xffff0000u));
    unsigned off = accb + ((((unsigned)rl << 6) + (unsigned)lane) << 2);
    // plane0 at off, plane1 at off + BROWS*64*4 = 16384 (free imm offset)
    asm volatile("ds_add_f32 %0, %1\n\t"
                 "ds_add_f32 %0, %2 offset:16384"
                 :: "v"(off), "v"(w * lo), "v"(w * hi) : "memory");
}

__global__ void __launch_bounds__(512, 8) bucket_accum(
        const int* __restrict__ fill, const uint2* __restrict__ inter,
        const unsigned* __restrict__ xb,   // [N,64] bf16x2
        float* __restrict__ out) {
    int b = blockIdx.x, g = blockIdx.y;
    int base = g ? (G1TOT + b * CAP2) : (b * CAP1);
    int cnt  = fill[g * NBUCK + b] - base;
    const uint2* rec = inter + base;

    __shared__ float acc[2 * BROWS * 64];        // 32 KB
    unsigned accb = (unsigned)(unsigned long long)(void*)acc;  // LDS byte offset
    int t = threadIdx.x, lane = t & 63, wid = t >> 6;
    for (int i = t; i < 2 * BROWS * 64; i += 512) acc[i] = 0.f;
    __syncthreads();

    // strided batches of 4 records per wave; 4 gathers in flight + pipelining
    int j = wid * 4;
    for (; j + 4 <= cnt; j += 8 * 4) {
        const uint4* rp = (const uint4*)(rec + j);   // 16B-aligned (caps %2==0)
        uint4 a = rp[0];                              // recs j, j+1
        uint4 c = rp[1];                              // recs j+2, j+3
        unsigned p0 = xb[(a.y & 0xffffu) * 64u + (unsigned)lane];
        unsigned p1 = xb[(a.w & 0xffffu) * 64u + (unsigned)lane];
        unsigned p2 = xb[(c.y & 0xffffu) * 64u + (unsigned)lane];
        unsigned p3 = xb[(c.w & 0xffffu) * 64u + (unsigned)lane];
        acc_rec(accb, lane, a.x, a.y, p0);
        acc_rec(accb, lane, a.z, a.w, p1);
        acc_rec(accb, lane, c.x, c.y, p2);
        acc_rec(accb, lane, c.z, c.w, p3);
    }
    // tail (<=3 records, exactly one wave lands here)
    for (int k = j; k < cnt; ++k) {
        uint2 v = rec[k];
        unsigned p = xb[(v.y & 0xffffu) * 64u + (unsigned)lane];
        acc_rec(accb, lane, v.x, v.y, p);
    }
    // drain our asm ds_add_f32 ops (compiler doesn't track them), then barrier
    asm volatile("s_waitcnt lgkmcnt(0)" ::: "memory");
    __syncthreads();

    // epilogue: coalesced nontemporal store of the bucket's out rows
    for (int row = wid; row < BROWS; row += 8) {
        int grow = (b << BSHIFT) + row;
        if (grow >= N_NODES) break;
        vf2 r;
        r.x = acc[(row << 6) + lane];
        r.y = acc[BROWS * 64 + (row << 6) + lane];
        vf2* o = (vf2*)(out + (size_t)grow * OUT_STRIDE + g * D);
        __builtin_nontemporal_store(r, o + lane);
    }
}

// ---------------- atomic scatter (fallback if ws too small) ----------------

__global__ void spmm_scatter(const float* __restrict__ x,
                             const int* __restrict__ ei,
                             const float* __restrict__ w,
                             float* __restrict__ out,
                             int E, int col_off) {
    long long gid = (long long)blockIdx.x * blockDim.x + threadIdx.x;
    int e    = (int)(gid >> 5);
    int lane = (int)(gid & 31);
    if (e >= E) return;
    int row  = ei[e];
    int col  = ei[E + e];
    float wv = w[e];
    const float4* xv = (const float4*)(x + (size_t)col * D);
    float4 v = xv[lane];
    float* o = out + (size_t)row * OUT_STRIDE + col_off + lane * 4;
    atomicAdd(o + 0, wv * v.x);
    atomicAdd(o + 1, wv * v.y);
    atomicAdd(o + 2, wv * v.z);
    atomicAdd(o + 3, wv * v.w);
}

extern "C" void kernel_launch(void* const* d_in, const int* in_sizes, int n_in,
                              void* d_out, int out_size, void* d_ws, size_t ws_size,
                              hipStream_t stream) {
    const float* x   = (const float*)d_in[0];
    const int*   ei1 = (const int*)d_in[1];
    const float* w1  = (const float*)d_in[2];
    const int*   ei2 = (const int*)d_in[3];
    const float* w2  = (const float*)d_in[4];
    float* out = (float*)d_out;

    const int E1 = in_sizes[1] / 2;   // 800000
    const int E2 = in_sizes[3] / 2;   // 1600000
    const int block = 256;

    // Workspace: fill | inter slabs | xb
    size_t fill_b  = align256((size_t)2 * NBUCK * sizeof(int));
    size_t inter_b = align256((size_t)(G1TOT + (size_t)NBUCK * CAP2) * sizeof(uint2));
    size_t xb_b    = align256((size_t)N_NODES * 64 * sizeof(unsigned));
    size_t o_fill  = 0;
    size_t o_int   = o_fill + fill_b;
    size_t o_xb    = o_int + inter_b;
    size_t needed  = o_xb + xb_b;

    // Slab caps assume E1/E2 near the spec sizes (+>=7 sigma headroom).
    bool cap_ok = (E1 <= 900000) && (E2 <= 1800000);

    if (ws_size < needed || !cap_ok) {
        // Fallback: atomic scatter (round-0).
        (void)hipMemsetAsync(d_out, 0, (size_t)out_size * sizeof(float), stream);
        long long th1 = (long long)E1 * 32;
        spmm_scatter<<<(int)((th1 + block - 1) / block), block, 0, stream>>>(
            x, ei1, w1, out, E1, 0);
        long long th2 = (long long)E2 * 32;
        spmm_scatter<<<(int)((th2 + block - 1) / block), block, 0, stream>>>(
            x, ei2, w2, out, E2, D);
        return;
    }

    char* ws = (char*)d_ws;
    int*      fill  = (int*)(ws + o_fill);
    uint2*    inter = (uint2*)(ws + o_int);
    unsigned* xb    = (unsigned*)(ws + o_xb);

    // 1. slab cursors
    init_fill<<<(NBUCK + block - 1) / block, block, 0, stream>>>(fill);

    // 2. pack x to bf16x2
    {
        int n4 = N_NODES * 32;
        cvt_bf16<<<(n4 + block - 1) / block, block, 0, stream>>>(
            x, (uint2*)xb, n4);
    }

    // 3. binned scatter into bucket slabs
    {
        int nch1 = (E1 + CHUNK - 1) / CHUNK;
        int nch2 = (E2 + CHUNK - 1) / CHUNK;
        bin_scatter<<<nch1 + nch2, block, 0, stream>>>(
            ei1, w1, E1, nch1, ei2, w2, E2, fill, inter);
    }

    // 4. gather + LDS f32 accumulate + coalesced out write
    {
        dim3 g(NBUCK, 2);
        bucket_accum<<<g, 512, 0, stream>>>(fill, inter, xb, out);
    }
}

// Round 3
// 246.630 us; speedup vs baseline: 8.1364x; 8.1364x over previous
//
#include <hip/hip_runtime.h>

// H2GCNConv: out[:, 0:128]   = segment_sum(w1 * x[col1], row1)
//            out[:, 128:256] = segment_sum(w2 * x[col2], row2)
// N = 50000, d = 128, out stride = 256 floats.
//
// Round 9: rounds 7/8 proved LDS FP32 atomics are a pipe dead-end on gfx950:
// CAS-loop and native ds_add_f32 both land at ~240 cy per wave-op (1870us,
// VALUBusy 2.2%), while int LDS atomics are fast (bin_scatter). So: keep the
// slab structure (no global hist/scan/sort kernels, no colw round-trip) but
// do the row-sort IN the accum kernel with int atomics, then accumulate in
// REGISTERS per row (round-6 spmm's proven inner loop, 23 cy/record), with
// records broadcast from LDS instead of global colw.
// Pipeline: init_fill -> cvt_bf16 -> bin_scatter -> bucket_accum.

#define N_NODES 50000
#define D 128
#define OUT_STRIDE 256

#define BSHIFT 6                       // 64 rows / bucket
#define BROWS (1 << BSHIFT)
#define NBUCK ((N_NODES + BROWS - 1) >> BSHIFT)   // 782
#define CAP1 1408                      // slab cap, graph1 (mean 1023, +12 sigma)
#define CAP2 2560                      // slab cap, graph2 (mean 2046, +11 sigma)
#define CAPMAX CAP2
#define G1TOT (NBUCK * CAP1)
#define CHUNK 7168                     // edges per bin_scatter WG

typedef float vf2 __attribute__((ext_vector_type(2)));

static inline size_t align256(size_t x) { return (x + 255) & ~(size_t)255; }

__device__ __forceinline__ unsigned f32_to_bf16_bits(float f) {
    unsigned u = __float_as_uint(f);
    return (u + 0x7fffu + ((u >> 16) & 1u)) >> 16;   // RNE
}

// ---------------- 1. init slab write cursors (no hist, no scan) ------------

__global__ void init_fill(int* __restrict__ fill) {
    int i = blockIdx.x * blockDim.x + threadIdx.x;
    if (i < NBUCK) {
        fill[i]         = i * CAP1;            // absolute record index
        fill[NBUCK + i] = G1TOT + i * CAP2;
    }
}

// ---------------- 2. binned scatter: edges -> bucket slabs -----------------

__global__ void __launch_bounds__(256) bin_scatter(
        const int* __restrict__ ei1, const float* __restrict__ w1, int E1, int nch1,
        const int* __restrict__ ei2, const float* __restrict__ w2, int E2,
        int* __restrict__ fill, uint2* __restrict__ inter) {
    int g, chunk;
    if ((int)blockIdx.x < nch1) { g = 0; chunk = blockIdx.x; }
    else                        { g = 1; chunk = blockIdx.x - nch1; }
    const int*   ei = g ? ei2 : ei1;
    const float* w  = g ? w2  : w1;
    int E           = g ? E2  : E1;
    int cap         = g ? CAP2 : CAP1;
    int* fcur       = fill + g * NBUCK;
    int e0  = chunk * CHUNK;
    int cnt = min(CHUNK, E - e0);

    __shared__ uint2 stage[CHUNK];              // 56 KB
    __shared__ int cntb[NBUCK], cur[NBUCK], gbase[NBUCK];   // 3 x 3.1 KB
    __shared__ int wsum[4];
    int t = threadIdx.x, lane = t & 63, wid = t >> 6;
    for (int b = t; b < NBUCK; b += 256) cntb[b] = 0;
    __syncthreads();
    // pass 1: count bins
    for (int i = t; i < cnt; i += 256)
        atomicAdd(&cntb[ei[e0 + i] >> BSHIFT], 1);
    __syncthreads();
    // exclusive scan over 782 bins (4 elems/thread, element-ordered quads)
    {
        int i0 = 4 * t;
        int v0 = (i0 + 0 < NBUCK) ? cntb[i0 + 0] : 0;
        int v1 = (i0 + 1 < NBUCK) ? cntb[i0 + 1] : 0;
        int v2 = (i0 + 2 < NBUCK) ? cntb[i0 + 2] : 0;
        int v3 = (i0 + 3 < NBUCK) ? cntb[i0 + 3] : 0;
        int p = v0 + v1 + v2 + v3, s = p;
        #pragma unroll
        for (int d = 1; d < 64; d <<= 1) { int u = __shfl_up(s, d, 64); if (lane >= d) s += u; }
        if (lane == 63) wsum[wid] = s;
        __syncthreads();
        int add = 0;
        #pragma unroll
        for (int k = 0; k < 4; ++k) if (k < wid) add += wsum[k];
        s += add;
        int e = s - p;
        if (i0 + 0 < NBUCK) cur[i0 + 0] = e;
        if (i0 + 1 < NBUCK) cur[i0 + 1] = e + v0;
        if (i0 + 2 < NBUCK) cur[i0 + 2] = e + v0 + v1;
        if (i0 + 3 < NBUCK) cur[i0 + 3] = e + v0 + v1 + v2;
    }
    __syncthreads();
    // reserve slab space per bin (absolute record indices)
    for (int b = t; b < NBUCK; b += 256) {
        int c = cntb[b];
        gbase[b] = c ? atomicAdd(&fcur[b], c) : 0;
    }
    __syncthreads();
    // pass 2: rank + stage
    for (int i = t; i < cnt; i += 256) {
        int row = ei[e0 + i];
        int col = ei[E + e0 + i];
        unsigned rec = (unsigned)col | (f32_to_bf16_bits(w[e0 + i]) << 16);
        int b = row >> BSHIFT;
        int pos = atomicAdd(&cur[b], 1);
        stage[pos] = make_uint2((unsigned)(row & (BROWS - 1)), rec);
    }
    __syncthreads();
    // flush each bin as a contiguous burst (wave per bin, round-robin);
    // clamp to slab end so an overflowing bin can never corrupt its neighbor
    for (int b = wid; b < NBUCK; b += 4) {
        int c = cntb[b];
        if (!c) continue;
        int s0 = cur[b] - c;          // cur[b] is now end-of-bin in stage
        int gb = gbase[b];
        int slab0 = (g ? G1TOT + b * CAP2 : b * CAP1);
        int wlim = min(c, slab0 + cap - gb);      // records that fit
        for (int i = lane; i < wlim; i += 64)
            inter[gb + i] = stage[s0 + i];
    }
}

// ---------------- 3. x -> bf16x2 pack --------------------------------------

__global__ void cvt_bf16(const float* __restrict__ x, uint2* __restrict__ xb4, int n4) {
    int i = blockIdx.x * blockDim.x + threadIdx.x;
    if (i >= n4) return;
    float4 v = ((const float4*)x)[i];
    unsigned a = f32_to_bf16_bits(v.x);
    unsigned b = f32_to_bf16_bits(v.y);
    unsigned c = f32_to_bf16_bits(v.z);
    unsigned d = f32_to_bf16_bits(v.w);
    xb4[i] = make_uint2(a | (b << 16), c | (d << 16));
}

// ---------------- 4. bucket accum: in-LDS row sort + register gather -------
// One WG per (bucket, graph). Int-atomic counting sort groups the slab's
// records by row inside LDS; then each wave register-accumulates 8 rows with
// the round-6 spmm inner loop (records broadcast from LDS, x gathered from
// global bf16x2). No FP atomics anywhere.

__device__ __forceinline__ void fma_rec(unsigned p, unsigned rec, float& ax, float& ay) {
    float w = __int_as_float((int)(rec & 0xffff0000u));   // bf16 bits already high
    ax += w * __int_as_float((int)(p << 16));
    ay += w * __int_as_float((int)(p & 0xffff0000u));
}

__global__ void __launch_bounds__(512, 8) bucket_accum(
        const int* __restrict__ fill, const uint2* __restrict__ inter,
        const unsigned* __restrict__ xb,   // [N,64] bf16x2
        float* __restrict__ out) {
    int b = blockIdx.x, g = blockIdx.y;
    int cap  = g ? CAP2 : CAP1;
    int base = g ? (G1TOT + b * CAP2) : (b * CAP1);
    int cnt  = min(fill[g * NBUCK + b] - base, cap);
    const uint2* rec = inter + base;

    __shared__ unsigned char rl[CAPMAX];   // 2.5 KB  row-local per record
    __shared__ unsigned recs[CAPMAX];      // 10 KB   col|w payload (load order)
    __shared__ unsigned outb[CAPMAX];      // 10 KB   row-sorted payload
    __shared__ int crow[BROWS], cur[BROWS], rstart[BROWS];
    int t = threadIdx.x, lane = t & 63, wid = t >> 6;
    if (t < BROWS) crow[t] = 0;
    __syncthreads();
    // load slab (coalesced) + count rows (int LDS atomics: fast)
    for (int i = t; i < cnt; i += 512) {
        uint2 v = rec[i];
        rl[i] = (unsigned char)v.x;
        recs[i] = v.y;
        atomicAdd(&crow[v.x], 1);
    }
    __syncthreads();
    // wave 0: exclusive scan of 64 row counts
    if (wid == 0) {
        int v = crow[lane], s = v;
        #pragma unroll
        for (int d = 1; d < 64; d <<= 1) { int u = __shfl_up(s, d, 64); if (lane >= d) s += u; }
        cur[lane] = s - v;
        rstart[lane] = s - v;
    }
    __syncthreads();
    // rank-scatter into row-sorted order
    for (int i = t; i < cnt; i += 512) {
        int pos = atomicAdd(&cur[rl[i]], 1);
        outb[pos] = recs[i];
    }
    __syncthreads();                   // cur[r] is now end-of-row r
    // each wave register-accumulates 8 rows
    for (int r = wid * 8; r < wid * 8 + 8; ++r) {
        int grow = (b << BSHIFT) + r;
        if (grow >= N_NODES) break;
        int s0 = rstart[r], e0 = cur[r];
        float ax = 0.f, ay = 0.f;
        int j = s0;
        for (; j + 4 <= e0; j += 4) {
            unsigned c0 = outb[j];
            unsigned c1 = outb[j + 1];
            unsigned c2 = outb[j + 2];
            unsigned c3 = outb[j + 3];
            unsigned p0 = xb[(size_t)(c0 & 0xffffu) * 64 + lane];
            unsigned p1 = xb[(size_t)(c1 & 0xffffu) * 64 + lane];
            unsigned p2 = xb[(size_t)(c2 & 0xffffu) * 64 + lane];
            unsigned p3 = xb[(size_t)(c3 & 0xffffu) * 64 + lane];
            fma_rec(p0, c0, ax, ay);
            fma_rec(p1, c1, ax, ay);
            fma_rec(p2, c2, ax, ay);
            fma_rec(p3, c3, ax, ay);
        }
        for (; j < e0; ++j) {
            unsigned c = outb[j];
            unsigned p = xb[(size_t)(c & 0xffffu) * 64 + lane];
            fma_rec(p, c, ax, ay);
        }
        vf2 rv; rv.x = ax; rv.y = ay;
        vf2* o = (vf2*)(out + (size_t)grow * OUT_STRIDE + g * D);
        __builtin_nontemporal_store(rv, o + lane);
    }
}

// ---------------- atomic scatter (fallback if ws too small) ----------------

__global__ void spmm_scatter(const float* __restrict__ x,
                             const int* __restrict__ ei,
                             const float* __restrict__ w,
                             float* __restrict__ out,
                             int E, int col_off) {
    long long gid = (long long)blockIdx.x * blockDim.x + threadIdx.x;
    int e    = (int)(gid >> 5);
    int lane = (int)(gid & 31);
    if (e >= E) return;
    int row  = ei[e];
    int col  = ei[E + e];
    float wv = w[e];
    const float4* xv = (const float4*)(x + (size_t)col * D);
    float4 v = xv[lane];
    float* o = out + (size_t)row * OUT_STRIDE + col_off + lane * 4;
    atomicAdd(o + 0, wv * v.x);
    atomicAdd(o + 1, wv * v.y);
    atomicAdd(o + 2, wv * v.z);
    atomicAdd(o + 3, wv * v.w);
}

extern "C" void kernel_launch(void* const* d_in, const int* in_sizes, int n_in,
                              void* d_out, int out_size, void* d_ws, size_t ws_size,
                              hipStream_t stream) {
    const float* x   = (const float*)d_in[0];
    const int*   ei1 = (const int*)d_in[1];
    const float* w1  = (const float*)d_in[2];
    const int*   ei2 = (const int*)d_in[3];
    const float* w2  = (const float*)d_in[4];
    float* out = (float*)d_out;

    const int E1 = in_sizes[1] / 2;   // 800000
    const int E2 = in_sizes[3] / 2;   // 1600000
    const int block = 256;

    // Workspace: fill | inter slabs | xb
    size_t fill_b  = align256((size_t)2 * NBUCK * sizeof(int));
    size_t inter_b = align256((size_t)(G1TOT + (size_t)NBUCK * CAP2) * sizeof(uint2));
    size_t xb_b    = align256((size_t)N_NODES * 64 * sizeof(unsigned));
    size_t o_fill  = 0;
    size_t o_int   = o_fill + fill_b;
    size_t o_xb    = o_int + inter_b;
    size_t needed  = o_xb + xb_b;

    // Slab caps assume E1/E2 near the spec sizes (+>=7 sigma headroom).
    bool cap_ok = (E1 <= 900000) && (E2 <= 1800000);

    if (ws_size < needed || !cap_ok) {
        // Fallback: atomic scatter (round-0).
        (void)hipMemsetAsync(d_out, 0, (size_t)out_size * sizeof(float), stream);
        long long th1 = (long long)E1 * 32;
        spmm_scatter<<<(int)((th1 + block - 1) / block), block, 0, stream>>>(
            x, ei1, w1, out, E1, 0);
        long long th2 = (long long)E2 * 32;
        spmm_scatter<<<(int)((th2 + block - 1) / block), block, 0, stream>>>(
            x, ei2, w2, out, E2, D);
        return;
    }

    char* ws = (char*)d_ws;
    int*      fill  = (int*)(ws + o_fill);
    uint2*    inter = (uint2*)(ws + o_int);
    unsigned* xb    = (unsigned*)(ws + o_xb);

    // 1. slab cursors
    init_fill<<<(NBUCK + block - 1) / block, block, 0, stream>>>(fill);

    // 2. pack x to bf16x2
    {
        int n4 = N_NODES * 32;
        cvt_bf16<<<(n4 + block - 1) / block, block, 0, stream>>>(
            x, (uint2*)xb, n4);
    }

    // 3. binned scatter into bucket slabs
    {
        int nch1 = (E1 + CHUNK - 1) / CHUNK;
        int nch2 = (E2 + CHUNK - 1) / CHUNK;
        bin_scatter<<<nch1 + nch2, block, 0, stream>>>(
            ei1, w1, E1, nch1, ei2, w2, E2, fill, inter);
    }

    // 4. in-LDS row sort + register-accumulate gather
    {
        dim3 g(NBUCK, 2);
        bucket_accum<<<g, 512, 0, stream>>>(fill, inter, xb, out);
    }
}

// Round 4
// 212.133 us; speedup vs baseline: 9.4595x; 1.1626x over previous
//
#include <hip/hip_runtime.h>

// H2GCNConv: out[:, 0:128]   = segment_sum(w1 * x[col1], row1)
//            out[:, 128:256] = segment_sum(w2 * x[col2], row2)
// N = 50000, d = 128, out stride = 256 floats.
//
// Round 10: round-9 accounting: bucket_accum = 83.5us but total = 246.6us ->
// bin_scatter ~ 100-130us, dominated by (a) 263K device-scope atomicAdds on
// 1564 hot fill words (~170 serialized L2 RMWs per address) and (b) random
// ~74B burst writes to slab offsets (partial-line RMW + empty-lane flush
// loop). Fix: chunk-major layout. Each chunk WG bin-sorts in LDS (as before)
// but writes its records CONTIGUOUSLY at inter[cid*CHUNK] (coalesced, full
// lines, no atomics) + per-chunk bin ends to ends[cid][b]. bucket_accum
// assembles bucket b from ~87/174 short segments (read-side fragmentation is
// L1/L2-absorbed and fully parallel). init_fill + fill array + slab caps die.
// Pipeline: cvt_bf16 -> bin_scatter -> bucket_accum.

#define N_NODES 50000
#define D 128
#define OUT_STRIDE 256

#define BSHIFT 6                       // 64 rows / bucket
#define BROWS (1 << BSHIFT)
#define NBUCK ((N_NODES + BROWS - 1) >> BSHIFT)   // 782
#define CHUNK 9216                     // edges per bin_scatter WG (72 KB stage)
#define CAPB 3072                      // per-bucket LDS cap (g2 mean 2046, +22 sigma)

typedef float vf2 __attribute__((ext_vector_type(2)));

static inline size_t align256(size_t x) { return (x + 255) & ~(size_t)255; }

__device__ __forceinline__ unsigned f32_to_bf16_bits(float f) {
    unsigned u = __float_as_uint(f);
    return (u + 0x7fffu + ((u >> 16) & 1u)) >> 16;   // RNE
}

// ---------------- 1. binned scatter: chunk -> bin-sorted contiguous block --

__global__ void __launch_bounds__(512) bin_scatter(
        const int* __restrict__ ei1, const float* __restrict__ w1, int E1, int nch1,
        const int* __restrict__ ei2, const float* __restrict__ w2, int E2,
        uint2* __restrict__ inter, int* __restrict__ ends) {
    int cid = blockIdx.x;
    int g = (cid < nch1) ? 0 : 1;
    int chunk = g ? cid - nch1 : cid;
    const int*   ei = g ? ei2 : ei1;
    const float* w  = g ? w2  : w1;
    int E           = g ? E2  : E1;
    int e0  = chunk * CHUNK;
    int cnt = min(CHUNK, E - e0);

    __shared__ uint2 stage[CHUNK];              // 72 KB
    __shared__ int cntb[NBUCK], cur[NBUCK];     // 2 x 3.1 KB
    __shared__ int wsum[8];
    int t = threadIdx.x, lane = t & 63, wid = t >> 6;
    for (int b = t; b < NBUCK; b += 512) cntb[b] = 0;
    __syncthreads();
    // pass 1: count bins (int LDS atomics)
    for (int i = t; i < cnt; i += 512)
        atomicAdd(&cntb[ei[e0 + i] >> BSHIFT], 1);
    __syncthreads();
    // exclusive scan over 782 bins (2 elems/thread, 8 waves)
    {
        int i0 = 2 * t;
        int v0 = (i0     < NBUCK) ? cntb[i0]     : 0;
        int v1 = (i0 + 1 < NBUCK) ? cntb[i0 + 1] : 0;
        int p = v0 + v1, s = p;
        #pragma unroll
        for (int d = 1; d < 64; d <<= 1) { int u = __shfl_up(s, d, 64); if (lane >= d) s += u; }
        if (lane == 63) wsum[wid] = s;
        __syncthreads();
        int add = 0;
        #pragma unroll
        for (int k = 0; k < 8; ++k) if (k < wid) add += wsum[k];
        s += add;
        int e = s - p;
        if (i0     < NBUCK) cur[i0]     = e;
        if (i0 + 1 < NBUCK) cur[i0 + 1] = e + v0;
    }
    __syncthreads();
    // pass 2: rank + stage (bin-sorted within chunk)
    for (int i = t; i < cnt; i += 512) {
        int row = ei[e0 + i];
        int col = ei[E + e0 + i];
        unsigned rec = (unsigned)col | (f32_to_bf16_bits(w[e0 + i]) << 16);
        int b = row >> BSHIFT;
        int pos = atomicAdd(&cur[b], 1);
        stage[pos] = make_uint2((unsigned)(row & (BROWS - 1)), rec);
    }
    __syncthreads();
    // cur[b] is now end-of-bin b within this chunk: write ends + flush
    for (int b = t; b < NBUCK; b += 512)
        ends[(size_t)cid * NBUCK + b] = cur[b];
    for (int i = t; i < cnt; i += 512)
        inter[(size_t)cid * CHUNK + i] = stage[i];   // fully coalesced
}

// ---------------- 2. x -> bf16x2 pack --------------------------------------

__global__ void cvt_bf16(const float* __restrict__ x, uint2* __restrict__ xb4, int n4) {
    int i = blockIdx.x * blockDim.x + threadIdx.x;
    if (i >= n4) return;
    float4 v = ((const float4*)x)[i];
    unsigned a = f32_to_bf16_bits(v.x);
    unsigned b = f32_to_bf16_bits(v.y);
    unsigned c = f32_to_bf16_bits(v.z);
    unsigned d = f32_to_bf16_bits(v.w);
    xb4[i] = make_uint2(a | (b << 16), c | (d << 16));
}

// ---------------- 3. bucket accum: segment gather + row sort + registers ---
// One WG per (bucket, graph). Phase A collects the bucket's records from all
// chunks' segments into LDS (position via one fast int LDS atomic per
// segment), counts rows; then scan + rank-scatter groups by row; then each
// wave register-accumulates 8 rows (round-6 spmm inner loop). No FP atomics,
// no global atomics anywhere.

__device__ __forceinline__ void fma_rec(unsigned p, unsigned rec, float& ax, float& ay) {
    float w = __int_as_float((int)(rec & 0xffff0000u));   // bf16 bits already high
    ax += w * __int_as_float((int)(p << 16));
    ay += w * __int_as_float((int)(p & 0xffff0000u));
}

__global__ void __launch_bounds__(512, 4) bucket_accum(
        const uint2* __restrict__ inter, const int* __restrict__ ends,
        const unsigned* __restrict__ xb,   // [N,64] bf16x2
        float* __restrict__ out, int nch1, int nch2) {
    int b = blockIdx.x, g = blockIdx.y;
    int c0 = g ? nch1 : 0;
    int nc = g ? nch2 : nch1;

    __shared__ unsigned char rl[CAPB];     // 3 KB   row-local per record
    __shared__ unsigned recs[CAPB];        // 12 KB  payload (load order)
    __shared__ unsigned outb[CAPB];        // 12 KB  row-sorted payload
    __shared__ int crow[BROWS], cur[BROWS], rstart[BROWS];
    __shared__ int total;
    int t = threadIdx.x, lane = t & 63, wid = t >> 6;
    if (t < BROWS) crow[t] = 0;
    if (t == 0) total = 0;
    __syncthreads();
    // phase A: pull this bucket's segment from each chunk
    for (int ci = t; ci < nc; ci += 512) {
        const int* ep = ends + (size_t)(c0 + ci) * NBUCK;
        int s = b ? ep[b - 1] : 0;
        int e = ep[b];
        int n = e - s;
        if (!n) continue;
        int dst = atomicAdd(&total, n);    // LDS int atomic: fast
        const uint2* src = inter + (size_t)(c0 + ci) * CHUNK + s;
        int k = 0;
        for (; k + 2 <= n; k += 2) {       // 2 loads in flight
            uint2 a  = src[k];
            uint2 b2 = src[k + 1];
            int p0 = dst + k, p1 = dst + k + 1;
            if (p0 < CAPB) { rl[p0] = (unsigned char)a.x;  recs[p0] = a.y;  atomicAdd(&crow[a.x], 1); }
            if (p1 < CAPB) { rl[p1] = (unsigned char)b2.x; recs[p1] = b2.y; atomicAdd(&crow[b2.x], 1); }
        }
        if (k < n) {
            uint2 a = src[k];
            int p0 = dst + k;
            if (p0 < CAPB) { rl[p0] = (unsigned char)a.x; recs[p0] = a.y; atomicAdd(&crow[a.x], 1); }
        }
    }
    __syncthreads();
    int cnt = min(total, CAPB);
    // wave 0: exclusive scan of 64 row counts
    if (wid == 0) {
        int v = crow[lane], s = v;
        #pragma unroll
        for (int d = 1; d < 64; d <<= 1) { int u = __shfl_up(s, d, 64); if (lane >= d) s += u; }
        cur[lane] = s - v;
        rstart[lane] = s - v;
    }
    __syncthreads();
    // rank-scatter into row-sorted order
    for (int i = t; i < cnt; i += 512) {
        int pos = atomicAdd(&cur[rl[i]], 1);
        outb[pos] = recs[i];
    }
    __syncthreads();                   // cur[r] is now end-of-row r
    // each wave register-accumulates 8 rows
    for (int r = wid * 8; r < wid * 8 + 8; ++r) {
        int grow = (b << BSHIFT) + r;
        if (grow >= N_NODES) break;
        int s0 = rstart[r], e0 = cur[r];
        float ax = 0.f, ay = 0.f;
        int j = s0;
        for (; j + 4 <= e0; j += 4) {
            unsigned c0r = outb[j];
            unsigned c1 = outb[j + 1];
            unsigned c2 = outb[j + 2];
            unsigned c3 = outb[j + 3];
            unsigned p0 = xb[(size_t)(c0r & 0xffffu) * 64 + lane];
            unsigned p1 = xb[(size_t)(c1 & 0xffffu) * 64 + lane];
            unsigned p2 = xb[(size_t)(c2 & 0xffffu) * 64 + lane];
            unsigned p3 = xb[(size_t)(c3 & 0xffffu) * 64 + lane];
            fma_rec(p0, c0r, ax, ay);
            fma_rec(p1, c1, ax, ay);
            fma_rec(p2, c2, ax, ay);
            fma_rec(p3, c3, ax, ay);
        }
        for (; j < e0; ++j) {
            unsigned c = outb[j];
            unsigned p = xb[(size_t)(c & 0xffffu) * 64 + lane];
            fma_rec(p, c, ax, ay);
        }
        vf2 rv; rv.x = ax; rv.y = ay;
        vf2* o = (vf2*)(out + (size_t)grow * OUT_STRIDE + g * D);
        __builtin_nontemporal_store(rv, o + lane);
    }
}

// ---------------- atomic scatter (fallback if ws too small) ----------------

__global__ void spmm_scatter(const float* __restrict__ x,
                             const int* __restrict__ ei,
                             const float* __restrict__ w,
                             float* __restrict__ out,
                             int E, int col_off) {
    long long gid = (long long)blockIdx.x * blockDim.x + threadIdx.x;
    int e    = (int)(gid >> 5);
    int lane = (int)(gid & 31);
    if (e >= E) return;
    int row  = ei[e];
    int col  = ei[E + e];
    float wv = w[e];
    const float4* xv = (const float4*)(x + (size_t)col * D);
    float4 v = xv[lane];
    float* o = out + (size_t)row * OUT_STRIDE + col_off + lane * 4;
    atomicAdd(o + 0, wv * v.x);
    atomicAdd(o + 1, wv * v.y);
    atomicAdd(o + 2, wv * v.z);
    atomicAdd(o + 3, wv * v.w);
}

extern "C" void kernel_launch(void* const* d_in, const int* in_sizes, int n_in,
                              void* d_out, int out_size, void* d_ws, size_t ws_size,
                              hipStream_t stream) {
    const float* x   = (const float*)d_in[0];
    const int*   ei1 = (const int*)d_in[1];
    const float* w1  = (const float*)d_in[2];
    const int*   ei2 = (const int*)d_in[3];
    const float* w2  = (const float*)d_in[4];
    float* out = (float*)d_out;

    const int E1 = in_sizes[1] / 2;   // 800000
    const int E2 = in_sizes[3] / 2;   // 1600000
    const int block = 256;

    int nch1 = (E1 + CHUNK - 1) / CHUNK;   // 87
    int nch2 = (E2 + CHUNK - 1) / CHUNK;   // 174
    int ncht = nch1 + nch2;                // 261

    // Workspace: ends | inter (chunk-major, exact) | xb
    size_t ends_b  = align256((size_t)ncht * NBUCK * sizeof(int));
    size_t inter_b = align256((size_t)ncht * CHUNK * sizeof(uint2));
    size_t xb_b    = align256((size_t)N_NODES * 64 * sizeof(unsigned));
    size_t o_ends  = 0;
    size_t o_int   = o_ends + ends_b;
    size_t o_xb    = o_int + inter_b;
    size_t needed  = o_xb + xb_b;

    if (ws_size < needed) {
        // Fallback: atomic scatter (round-0).
        (void)hipMemsetAsync(d_out, 0, (size_t)out_size * sizeof(float), stream);
        long long th1 = (long long)E1 * 32;
        spmm_scatter<<<(int)((th1 + block - 1) / block), block, 0, stream>>>(
            x, ei1, w1, out, E1, 0);
        long long th2 = (long long)E2 * 32;
        spmm_scatter<<<(int)((th2 + block - 1) / block), block, 0, stream>>>(
            x, ei2, w2, out, E2, D);
        return;
    }

    char* ws = (char*)d_ws;
    int*      ends  = (int*)(ws + o_ends);
    uint2*    inter = (uint2*)(ws + o_int);
    unsigned* xb    = (unsigned*)(ws + o_xb);

    // 1. pack x to bf16x2
    {
        int n4 = N_NODES * 32;
        cvt_bf16<<<(n4 + block - 1) / block, block, 0, stream>>>(
            x, (uint2*)xb, n4);
    }

    // 2. bin-sort chunks, write contiguously (no atomics, no scatter)
    bin_scatter<<<ncht, 512, 0, stream>>>(
        ei1, w1, E1, nch1, ei2, w2, E2, inter, ends);

    // 3. segment gather + in-LDS row sort + register accumulate
    {
        dim3 g(NBUCK, 2);
        bucket_accum<<<g, 512, 0, stream>>>(inter, ends, xb, out, nch1, nch2);
    }
}